// Round 2
// baseline (1397.483 us; speedup 1.0000x reference)
//
#include <hip/hip_runtime.h>
#include <cstddef>

// ---------------------------------------------------------------------------
// CLSTMCell fused as one bf16 GEMM + epilogue.
//   X (4096 x 4096)  = [xr | xi | hr | hi] rows  (bf16, packed in ws)
//   W (8192 x 4096)  rows n = o*8 + g*2 + p, k-quarters [UwR,-UwI,WwR,-WwI] (p=0)
//                                            [UwI, UwR, WwI, WwR]           (p=1)
//   z = X @ W^T + bias ; epilogue: gates -> c_t, h_t  (fp32 out)
// ---------------------------------------------------------------------------

typedef short bf16x8 __attribute__((ext_vector_type(8)));   // 8 bf16 (4 VGPRs)
typedef float f32x4  __attribute__((ext_vector_type(4)));
typedef unsigned int u32x4 __attribute__((ext_vector_type(4)));

static constexpr int KDIM = 4096;
static constexpr size_t HOFF = (size_t)4096 * 2048;   // out offset of c_t

__device__ __forceinline__ unsigned short f2bf(float f) {
    unsigned u = __float_as_uint(f);
    u += 0x7FFF + ((u >> 16) & 1);      // RNE
    return (unsigned short)(u >> 16);
}

__device__ __forceinline__ u32x4 pack8(float4 a, float4 b) {
    u32x4 v;
    v.x = (unsigned)f2bf(a.x) | ((unsigned)f2bf(a.y) << 16);
    v.y = (unsigned)f2bf(a.z) | ((unsigned)f2bf(a.w) << 16);
    v.z = (unsigned)f2bf(b.x) | ((unsigned)f2bf(b.y) << 16);
    v.w = (unsigned)f2bf(b.z) | ((unsigned)f2bf(b.w) << 16);
    return v;
}

__device__ __forceinline__ float4 neg4(float4 v) {
    return make_float4(-v.x, -v.y, -v.z, -v.w);
}

__device__ __forceinline__ void async16(const void* g, void* l) {
    __builtin_amdgcn_global_load_lds(
        (const __attribute__((address_space(1))) unsigned int*)g,
        (__attribute__((address_space(3))) unsigned int*)l,
        16, 0, 0);
}

__device__ __forceinline__ float sigm(float x) { return 1.0f / (1.0f + __expf(-x)); }
__device__ __forceinline__ float tanh_(float x) {
    float e = __expf(2.0f * x);          // |x| <~ 10 here, no overflow
    return (e - 1.0f) / (e + 1.0f);
}

// ------------------ merged pack: X rows + W (signs folded) + bias -----------
__global__ __launch_bounds__(256) void pack_all(
    const float* __restrict__ input, const float* __restrict__ hx,
    const float* __restrict__ Uw_r, const float* __restrict__ Uw_i,
    const float* __restrict__ Ww_r, const float* __restrict__ Ww_i,
    const float* __restrict__ Ub_r, const float* __restrict__ Ub_i,
    const float* __restrict__ Wb_r, const float* __restrict__ Wb_i,
    unsigned short* __restrict__ Xb, unsigned short* __restrict__ Wb16,
    float* __restrict__ biasp) {
    int bid = blockIdx.x;
    if (bid < 8192) {
        // ---- pack X = [input | h_x] rows ----
        int idx = bid * 256 + threadIdx.x;          // 2,097,152 chunks of 8
        int r    = idx >> 9;                        // row 0..4095
        int gcol = (idx & 511) * 8;                 // 0..4088
        const float* src = (gcol < 2048) ? (input + (size_t)r * 2048 + gcol)
                                         : (hx    + (size_t)r * 2048 + (gcol - 2048));
        float4 f0 = *(const float4*)src;
        float4 f1 = *(const float4*)(src + 4);
        *(u32x4*)(Xb + (size_t)idx * 8) = pack8(f0, f1);
    } else {
        // ---- pack W row-pairs + bias ----
        int idx = (bid - 8192) * 256 + threadIdx.x; // 2,097,152
        int np = idx >> 9;                          // o*4 + g, 0..4095
        int c8 = idx & 511;
        int k  = c8 * 8;                            // 0..4088
        int o = np >> 2, g = np & 3;
        int q = k >> 10, d = k & 1023;              // k-quarter, offset within
        size_t sidx = (size_t)g * (1024 * 1024) + (size_t)o * 1024 + d;
        const float* srcR = (q < 2 ? Uw_r : Ww_r) + sidx;
        const float* srcI = (q < 2 ? Uw_i : Ww_i) + sidx;
        float4 r0 = *(const float4*)srcR; float4 r1 = *(const float4*)(srcR + 4);
        float4 i0 = *(const float4*)srcI; float4 i1 = *(const float4*)(srcI + 4);
        int n0 = o * 8 + g * 2;
        u32x4 p0, p1;
        if (q & 1) { p0 = pack8(neg4(i0), neg4(i1)); p1 = pack8(r0, r1); }
        else       { p0 = pack8(r0, r1);             p1 = pack8(i0, i1); }
        *(u32x4*)(Wb16 + (size_t)n0 * KDIM + k)       = p0;
        *(u32x4*)(Wb16 + (size_t)(n0 + 1) * KDIM + k) = p1;
        if (c8 == 0) {
            size_t bi = (size_t)g * 1024 + o;
            biasp[n0]     = Ub_r[bi] + Wb_r[bi];
            biasp[n0 + 1] = Ub_i[bi] + Wb_i[bi];
        }
    }
}

// ------------------------- GEMM + fused epilogue ----------------------------
// block: 256 threads (4 waves, 2x2), C-tile 128x128, BK=64, 16x16x32 bf16 MFMA
// LDS exactly 32 KiB -> 5 blocks/CU (5 * 32768 = 160 KiB).
__global__ __launch_bounds__(256, 5) void clstm_gemm(
    const unsigned short* __restrict__ Xb,    // 4096 x 4096 bf16
    const unsigned short* __restrict__ Wb,    // 8192 x 4096 bf16
    const float* __restrict__ biasp,          // 8192
    const float* __restrict__ c_x,            // 4096 x 2048 fp32
    float* __restrict__ out) {
    __shared__ __align__(16) char smem[32768];  // staging 32KB; epilogue 4x8KB
    char* sA = smem;              // 128 x 64 bf16, row stride 128B, chunk-swizzled
    char* sB = smem + 16384;

    const int tid  = threadIdx.x;
    const int lane = tid & 63;
    const int wave = tid >> 6;
    const int wm = wave >> 1, wn = wave & 1;
    const int quad = lane >> 4, col16 = lane & 15;

    const int mblock = blockIdx.x >> 6;   // 0..31
    const int nblock = blockIdx.x & 63;   // 0..63

    // staging: lane writes LDS at waveBase + lane*16; global addr carries the
    // XOR swizzle: LDS slot s of row r holds global chunk s ^ (r&7)
    const int rbase = tid >> 3;                       // 0..31
    const int csw   = (tid & 7) ^ (rbase & 7);        // swizzled chunk 0..7
    const unsigned short* pa[4];
    const unsigned short* pb[4];
#pragma unroll
    for (int i = 0; i < 4; ++i) {
        pa[i] = Xb + (size_t)(mblock * 128 + i * 32 + rbase) * KDIM + csw * 8;
        pb[i] = Wb + (size_t)(nblock * 128 + i * 32 + rbase) * KDIM + csw * 8;
    }

    f32x4 acc[4][4] = {};

    for (int kt = 0; kt < 64; ++kt) {
        __syncthreads();                       // prev tile's reads done
#pragma unroll
        for (int i = 0; i < 4; ++i) {
            async16(pa[i], sA + i * 4096 + wave * 1024);
            async16(pb[i], sB + i * 4096 + wave * 1024);
            pa[i] += 64; pb[i] += 64;
        }
        __syncthreads();                       // vmcnt(0) drain + barrier
#pragma unroll
        for (int s = 0; s < 2; ++s) {
            bf16x8 af[4], bf[4];
#pragma unroll
            for (int t = 0; t < 4; ++t) {
                int mr = wm * 64 + t * 16 + col16;
                int ch = (s * 4 + quad) ^ (mr & 7);
                af[t] = *(const bf16x8*)(sA + mr * 128 + ch * 16);
                int nr = wn * 64 + t * 16 + col16;
                int ch2 = (s * 4 + quad) ^ (nr & 7);
                bf[t] = *(const bf16x8*)(sB + nr * 128 + ch2 * 16);
            }
#pragma unroll
            for (int tm = 0; tm < 4; ++tm)
#pragma unroll
                for (int tn = 0; tn < 4; ++tn)
                    acc[tm][tn] = __builtin_amdgcn_mfma_f32_16x16x32_bf16(
                        af[tm], bf[tn], acc[tm][tn], 0, 0, 0);
        }
    }

    // ---- epilogue: per-wave LDS round trip, C-layout -> (row, o) layout ----
    // zs is WAVE-PRIVATE (disjoint 8KB regions): one barrier total, then only
    // intra-wave lgkmcnt ordering (compiler-inserted) is needed.
    __syncthreads();                             // all waves' K-loop LDS reads done
    float* zs = (float*)(smem + wave * 8192);    // 32 rows x 40 f32 = 5120B used
    const float* bp = biasp + nblock * 128 + wn * 64;
    const int o_idx = lane & 3;
    const int rgrp  = lane >> 2;                 // 0..15

    for (int p = 0; p < 4; ++p) {                // {col half h} x {row seg}
        const int h   = p >> 1;
        const int seg = p & 1;                   // tm base = seg*2
#pragma unroll
        for (int tm2 = 0; tm2 < 2; ++tm2)
#pragma unroll
            for (int tl = 0; tl < 2; ++tl) {
                int tn = h * 2 + tl;
                int colz = tl * 16 + col16;
#pragma unroll
                for (int r = 0; r < 4; ++r)
                    zs[(tm2 * 16 + quad * 4 + r) * 40 + colz] = acc[seg * 2 + tm2][tn][r];
            }
        // intra-wave RAW through LDS: compiler inserts lgkmcnt wait

        float4 bb0 = *(const float4*)(bp + h * 32 + o_idx * 8);
        float4 bb1 = *(const float4*)(bp + h * 32 + o_idx * 8 + 4);
        int o_glob = nblock * 16 + wn * 8 + h * 4 + o_idx;

#pragma unroll
        for (int t = 0; t < 2; ++t) {
            int rowz = rgrp + t * 16;            // 0..31 within segment
            const float* zp = zs + rowz * 40 + o_idx * 8;
            float4 z0 = *(const float4*)zp;
            float4 z1 = *(const float4*)(zp + 4);
            int b = mblock * 128 + wm * 64 + seg * 32 + rowz;

            float fr = sigm(z0.x + bb0.x), fi = sigm(z0.y + bb0.y);
            float ir = sigm(z0.z + bb0.z), ii = sigm(z0.w + bb0.w);
            float ar = tanh_(z1.x + bb1.x), ai = tanh_(z1.y + bb1.y);
            float og_r = sigm(z1.z + bb1.z), og_i = sigm(z1.w + bb1.w);

            float cr = c_x[(size_t)b * 2048 + o_glob];
            float ci = c_x[(size_t)b * 2048 + 1024 + o_glob];

            float ct_r = (cr * fr - ci * fi) + (ar * ir - ai * ii);
            float ct_i = (cr * fi + ci * fr) + (ar * ii + ai * ir);
            float tr = tanh_(ct_r), ti = tanh_(ct_i);
            float ht_r = og_r * tr - og_i * ti;
            float ht_i = og_r * ti + og_i * tr;

            out[(size_t)b * 2048 + o_glob]               = ht_r;
            out[(size_t)b * 2048 + 1024 + o_glob]        = ht_i;
            out[HOFF + (size_t)b * 2048 + o_glob]        = ct_r;
            out[HOFF + (size_t)b * 2048 + 1024 + o_glob] = ct_i;
        }
        if (p < 3) __builtin_amdgcn_s_waitcnt(0);  // drain LDS reads before next
                                                   // pass overwrites zs (wave-
                                                   // private; no barrier needed)
    }
}

// ---------------------------------------------------------------------------
extern "C" void kernel_launch(void* const* d_in, const int* in_sizes, int n_in,
                              void* d_out, int out_size, void* d_ws, size_t ws_size,
                              hipStream_t stream) {
    const float* input = (const float*)d_in[0];
    const float* h_x   = (const float*)d_in[1];
    const float* c_x   = (const float*)d_in[2];
    const float* Uw_r  = (const float*)d_in[3];
    const float* Uw_i  = (const float*)d_in[4];
    const float* Ub_r  = (const float*)d_in[5];
    const float* Ub_i  = (const float*)d_in[6];
    const float* Ww_r  = (const float*)d_in[7];
    const float* Ww_i  = (const float*)d_in[8];
    const float* Wb_r  = (const float*)d_in[9];
    const float* Wb_i  = (const float*)d_in[10];
    float* out = (float*)d_out;

    // ws layout: X bf16 (32MB) | Wbig bf16 (64MB) | bias fp32 (32KB)  ~= 96MB
    unsigned short* Xb   = (unsigned short*)d_ws;
    unsigned short* Wb16 = Xb + (size_t)4096 * 4096;
    float* biasp = (float*)(Wb16 + (size_t)8192 * 4096);

    pack_all<<<16384, 256, 0, stream>>>(input, h_x, Uw_r, Uw_i, Ww_r, Ww_i,
                                        Ub_r, Ub_i, Wb_r, Wb_i, Xb, Wb16, biasp);
    clstm_gemm<<<2048, 256, 0, stream>>>(Xb, Wb16, biasp, c_x, out);
}

// Round 3
// 630.186 us; speedup vs baseline: 2.2176x; 2.2176x over previous
//
#include <hip/hip_runtime.h>
#include <cstddef>

// ---------------------------------------------------------------------------
// CLSTMCell fused as one bf16 GEMM + epilogue.
//   X (4096 x 4096)  = [xr | xi | hr | hi] rows  (bf16, packed in ws)
//   W (8192 x 4096)  rows n = o*8 + g*2 + p, k-quarters [UwR,-UwI,WwR,-WwI] (p=0)
//                                            [UwI, UwR, WwI, WwR]           (p=1)
//   z = X @ W^T + bias ; epilogue: gates -> c_t, h_t  (fp32 out)
// NOTE (R2 post-mortem): do NOT pass min-waves>4 in __launch_bounds__ — the
// VGPR cap (512/waves) falls below the 64-VGPR accumulator + staging and the
// compiler spills acc to scratch (R2: VGPR 88->48, WRITE_SIZE 130MB->2.9GB,
// MfmaUtil 37->9%). (256,4) caps at 128 VGPRs: non-binding (kernel uses ~88).
// ---------------------------------------------------------------------------

typedef short bf16x8 __attribute__((ext_vector_type(8)));   // 8 bf16 (4 VGPRs)
typedef float f32x4  __attribute__((ext_vector_type(4)));
typedef unsigned int u32x4 __attribute__((ext_vector_type(4)));

static constexpr int KDIM = 4096;
static constexpr size_t HOFF = (size_t)4096 * 2048;   // out offset of c_t

__device__ __forceinline__ unsigned short f2bf(float f) {
    unsigned u = __float_as_uint(f);
    u += 0x7FFF + ((u >> 16) & 1);      // RNE
    return (unsigned short)(u >> 16);
}

__device__ __forceinline__ u32x4 pack8(float4 a, float4 b) {
    u32x4 v;
    v.x = (unsigned)f2bf(a.x) | ((unsigned)f2bf(a.y) << 16);
    v.y = (unsigned)f2bf(a.z) | ((unsigned)f2bf(a.w) << 16);
    v.z = (unsigned)f2bf(b.x) | ((unsigned)f2bf(b.y) << 16);
    v.w = (unsigned)f2bf(b.z) | ((unsigned)f2bf(b.w) << 16);
    return v;
}

__device__ __forceinline__ float4 neg4(float4 v) {
    return make_float4(-v.x, -v.y, -v.z, -v.w);
}

__device__ __forceinline__ void async16(const void* g, void* l) {
    __builtin_amdgcn_global_load_lds(
        (const __attribute__((address_space(1))) unsigned int*)g,
        (__attribute__((address_space(3))) unsigned int*)l,
        16, 0, 0);
}

__device__ __forceinline__ float sigm(float x) { return 1.0f / (1.0f + __expf(-x)); }
__device__ __forceinline__ float tanh_(float x) {
    float e = __expf(2.0f * x);          // |x| <~ 10 here, no overflow
    return (e - 1.0f) / (e + 1.0f);
}

// ------------------ merged pack: X rows + W (signs folded) + bias -----------
__global__ __launch_bounds__(256) void pack_all(
    const float* __restrict__ input, const float* __restrict__ hx,
    const float* __restrict__ Uw_r, const float* __restrict__ Uw_i,
    const float* __restrict__ Ww_r, const float* __restrict__ Ww_i,
    const float* __restrict__ Ub_r, const float* __restrict__ Ub_i,
    const float* __restrict__ Wb_r, const float* __restrict__ Wb_i,
    unsigned short* __restrict__ Xb, unsigned short* __restrict__ Wb16,
    float* __restrict__ biasp) {
    int bid = blockIdx.x;
    if (bid < 8192) {
        // ---- pack X = [input | h_x] rows ----
        int idx = bid * 256 + threadIdx.x;          // 2,097,152 chunks of 8
        int r    = idx >> 9;                        // row 0..4095
        int gcol = (idx & 511) * 8;                 // 0..4088
        const float* src = (gcol < 2048) ? (input + (size_t)r * 2048 + gcol)
                                         : (hx    + (size_t)r * 2048 + (gcol - 2048));
        float4 f0 = *(const float4*)src;
        float4 f1 = *(const float4*)(src + 4);
        *(u32x4*)(Xb + (size_t)idx * 8) = pack8(f0, f1);
    } else {
        // ---- pack W row-pairs + bias ----
        int idx = (bid - 8192) * 256 + threadIdx.x; // 2,097,152
        int np = idx >> 9;                          // o*4 + g, 0..4095
        int c8 = idx & 511;
        int k  = c8 * 8;                            // 0..4088
        int o = np >> 2, g = np & 3;
        int q = k >> 10, d = k & 1023;              // k-quarter, offset within
        size_t sidx = (size_t)g * (1024 * 1024) + (size_t)o * 1024 + d;
        const float* srcR = (q < 2 ? Uw_r : Ww_r) + sidx;
        const float* srcI = (q < 2 ? Uw_i : Ww_i) + sidx;
        float4 r0 = *(const float4*)srcR; float4 r1 = *(const float4*)(srcR + 4);
        float4 i0 = *(const float4*)srcI; float4 i1 = *(const float4*)(srcI + 4);
        int n0 = o * 8 + g * 2;
        u32x4 p0, p1;
        if (q & 1) { p0 = pack8(neg4(i0), neg4(i1)); p1 = pack8(r0, r1); }
        else       { p0 = pack8(r0, r1);             p1 = pack8(i0, i1); }
        *(u32x4*)(Wb16 + (size_t)n0 * KDIM + k)       = p0;
        *(u32x4*)(Wb16 + (size_t)(n0 + 1) * KDIM + k) = p1;
        if (c8 == 0) {
            size_t bi = (size_t)g * 1024 + o;
            biasp[n0]     = Ub_r[bi] + Wb_r[bi];
            biasp[n0 + 1] = Ub_i[bi] + Wb_i[bi];
        }
    }
}

// ------------------------- GEMM + fused epilogue ----------------------------
// block: 256 threads (4 waves, 2x2), C-tile 128x128, BK=64, 16x16x32 bf16 MFMA
// LDS exactly 32 KiB -> 5 blocks/CU at VGPR<=102 (natural alloc ~88).
__global__ __launch_bounds__(256, 4) void clstm_gemm(
    const unsigned short* __restrict__ Xb,    // 4096 x 4096 bf16
    const unsigned short* __restrict__ Wb,    // 8192 x 4096 bf16
    const float* __restrict__ biasp,          // 8192
    const float* __restrict__ c_x,            // 4096 x 2048 fp32
    float* __restrict__ out) {
    __shared__ __align__(16) char smem[32768];  // staging 32KB; epilogue 4x8KB
    char* sA = smem;              // 128 x 64 bf16, row stride 128B, chunk-swizzled
    char* sB = smem + 16384;

    const int tid  = threadIdx.x;
    const int lane = tid & 63;
    const int wave = tid >> 6;
    const int wm = wave >> 1, wn = wave & 1;
    const int quad = lane >> 4, col16 = lane & 15;

    const int mblock = blockIdx.x >> 6;   // 0..31
    const int nblock = blockIdx.x & 63;   // 0..63

    // staging: lane writes LDS at waveBase + lane*16; global addr carries the
    // XOR swizzle: LDS slot s of row r holds global chunk s ^ (r&7)
    const int rbase = tid >> 3;                       // 0..31
    const int csw   = (tid & 7) ^ (rbase & 7);        // swizzled chunk 0..7
    const unsigned short* pa[4];
    const unsigned short* pb[4];
#pragma unroll
    for (int i = 0; i < 4; ++i) {
        pa[i] = Xb + (size_t)(mblock * 128 + i * 32 + rbase) * KDIM + csw * 8;
        pb[i] = Wb + (size_t)(nblock * 128 + i * 32 + rbase) * KDIM + csw * 8;
    }

    f32x4 acc[4][4] = {};

    for (int kt = 0; kt < 64; ++kt) {
        __syncthreads();                       // prev tile's reads done
#pragma unroll
        for (int i = 0; i < 4; ++i) {
            async16(pa[i], sA + i * 4096 + wave * 1024);
            async16(pb[i], sB + i * 4096 + wave * 1024);
            pa[i] += 64; pb[i] += 64;
        }
        __syncthreads();                       // vmcnt(0) drain + barrier
#pragma unroll
        for (int s = 0; s < 2; ++s) {
            bf16x8 af[4], bf[4];
#pragma unroll
            for (int t = 0; t < 4; ++t) {
                int mr = wm * 64 + t * 16 + col16;
                int ch = (s * 4 + quad) ^ (mr & 7);
                af[t] = *(const bf16x8*)(sA + mr * 128 + ch * 16);
                int nr = wn * 64 + t * 16 + col16;
                int ch2 = (s * 4 + quad) ^ (nr & 7);
                bf[t] = *(const bf16x8*)(sB + nr * 128 + ch2 * 16);
            }
#pragma unroll
            for (int tm = 0; tm < 4; ++tm)
#pragma unroll
                for (int tn = 0; tn < 4; ++tn)
                    acc[tm][tn] = __builtin_amdgcn_mfma_f32_16x16x32_bf16(
                        af[tm], bf[tn], acc[tm][tn], 0, 0, 0);
        }
    }

    // ---- epilogue: per-wave LDS round trip, C-layout -> (row, o) layout ----
    // zs is WAVE-PRIVATE (disjoint 8KB regions): one barrier total, then only
    // intra-wave lgkmcnt ordering (compiler-inserted) is needed.
    __syncthreads();                             // all waves' K-loop LDS reads done
    float* zs = (float*)(smem + wave * 8192);    // 32 rows x 40 f32 = 5120B used
    const float* bp = biasp + nblock * 128 + wn * 64;
    const int o_idx = lane & 3;
    const int rgrp  = lane >> 2;                 // 0..15

    for (int p = 0; p < 4; ++p) {                // {col half h} x {row seg}
        const int h   = p >> 1;
        const int seg = p & 1;                   // tm base = seg*2
#pragma unroll
        for (int tm2 = 0; tm2 < 2; ++tm2)
#pragma unroll
            for (int tl = 0; tl < 2; ++tl) {
                int tn = h * 2 + tl;
                int colz = tl * 16 + col16;
#pragma unroll
                for (int r = 0; r < 4; ++r)
                    zs[(tm2 * 16 + quad * 4 + r) * 40 + colz] = acc[seg * 2 + tm2][tn][r];
            }
        // intra-wave RAW through LDS: compiler inserts lgkmcnt wait

        float4 bb0 = *(const float4*)(bp + h * 32 + o_idx * 8);
        float4 bb1 = *(const float4*)(bp + h * 32 + o_idx * 8 + 4);
        int o_glob = nblock * 16 + wn * 8 + h * 4 + o_idx;

#pragma unroll
        for (int t = 0; t < 2; ++t) {
            int rowz = rgrp + t * 16;            // 0..31 within segment
            const float* zp = zs + rowz * 40 + o_idx * 8;
            float4 z0 = *(const float4*)zp;
            float4 z1 = *(const float4*)(zp + 4);
            int b = mblock * 128 + wm * 64 + seg * 32 + rowz;

            float fr = sigm(z0.x + bb0.x), fi = sigm(z0.y + bb0.y);
            float ir = sigm(z0.z + bb0.z), ii = sigm(z0.w + bb0.w);
            float ar = tanh_(z1.x + bb1.x), ai = tanh_(z1.y + bb1.y);
            float og_r = sigm(z1.z + bb1.z), og_i = sigm(z1.w + bb1.w);

            float cr = c_x[(size_t)b * 2048 + o_glob];
            float ci = c_x[(size_t)b * 2048 + 1024 + o_glob];

            float ct_r = (cr * fr - ci * fi) + (ar * ir - ai * ii);
            float ct_i = (cr * fi + ci * fr) + (ar * ii + ai * ir);
            float tr = tanh_(ct_r), ti = tanh_(ct_i);
            float ht_r = og_r * tr - og_i * ti;
            float ht_i = og_r * ti + og_i * tr;

            out[(size_t)b * 2048 + o_glob]               = ht_r;
            out[(size_t)b * 2048 + 1024 + o_glob]        = ht_i;
            out[HOFF + (size_t)b * 2048 + o_glob]        = ct_r;
            out[HOFF + (size_t)b * 2048 + 1024 + o_glob] = ct_i;
        }
        if (p < 3) __builtin_amdgcn_s_waitcnt(0);  // drain LDS reads before next
                                                   // pass overwrites zs (wave-
                                                   // private; no barrier needed)
    }
}

// ---------------------------------------------------------------------------
extern "C" void kernel_launch(void* const* d_in, const int* in_sizes, int n_in,
                              void* d_out, int out_size, void* d_ws, size_t ws_size,
                              hipStream_t stream) {
    const float* input = (const float*)d_in[0];
    const float* h_x   = (const float*)d_in[1];
    const float* c_x   = (const float*)d_in[2];
    const float* Uw_r  = (const float*)d_in[3];
    const float* Uw_i  = (const float*)d_in[4];
    const float* Ub_r  = (const float*)d_in[5];
    const float* Ub_i  = (const float*)d_in[6];
    const float* Ww_r  = (const float*)d_in[7];
    const float* Ww_i  = (const float*)d_in[8];
    const float* Wb_r  = (const float*)d_in[9];
    const float* Wb_i  = (const float*)d_in[10];
    float* out = (float*)d_out;

    // ws layout: X bf16 (32MB) | Wbig bf16 (64MB) | bias fp32 (32KB)  ~= 96MB
    unsigned short* Xb   = (unsigned short*)d_ws;
    unsigned short* Wb16 = Xb + (size_t)4096 * 4096;
    float* biasp = (float*)(Wb16 + (size_t)8192 * 4096);

    pack_all<<<16384, 256, 0, stream>>>(input, h_x, Uw_r, Uw_i, Ww_r, Ww_i,
                                        Ub_r, Ub_i, Wb_r, Wb_i, Xb, Wb16, biasp);
    clstm_gemm<<<2048, 256, 0, stream>>>(Xb, Wb16, biasp, c_x, out);
}

// Round 4
// 492.587 us; speedup vs baseline: 2.8370x; 1.2793x over previous
//
#include <hip/hip_runtime.h>
#include <cstddef>

// ---------------------------------------------------------------------------
// CLSTMCell fused as one bf16 GEMM + epilogue.
//   X (4096 x 4096)  = [xr | xi | hr | hi] rows  (bf16, packed in ws)
//   W (8192 x 4096)  rows n = o*8 + g*2 + p, k-quarters [UwR,-UwI,WwR,-WwI] (p=0)
//                                            [UwI, UwR, WwI, WwR]           (p=1)
//   z = X @ W^T + bias ; epilogue: gates -> c_t, h_t  (fp32 out)
//
// NOTE (R2/R3 post-mortem): do NOT pass a min-waves arg in __launch_bounds__.
//   (256,5): VGPR 88->48, acc spilled, 2.9GB scratch traffic, MfmaUtil 9%.
//   (256,4): compiler chased the 8-wave tier anyway -> VGPR 64, mild spill +
//            register-starved K-loop, MfmaUtil 26%, GEMM 459us.
//   plain (256): VGPR 88, MfmaUtil 37%, GEMM 339us.  Keep plain.
// ---------------------------------------------------------------------------

typedef short bf16x8 __attribute__((ext_vector_type(8)));   // 8 bf16 (4 VGPRs)
typedef float f32x4  __attribute__((ext_vector_type(4)));
typedef unsigned int u32x4 __attribute__((ext_vector_type(4)));

static constexpr int KDIM = 4096;
static constexpr size_t HOFF = (size_t)4096 * 2048;   // out offset of c_t

__device__ __forceinline__ unsigned short f2bf(float f) {
    unsigned u = __float_as_uint(f);
    u += 0x7FFF + ((u >> 16) & 1);      // RNE
    return (unsigned short)(u >> 16);
}

__device__ __forceinline__ u32x4 pack8(float4 a, float4 b) {
    u32x4 v;
    v.x = (unsigned)f2bf(a.x) | ((unsigned)f2bf(a.y) << 16);
    v.y = (unsigned)f2bf(a.z) | ((unsigned)f2bf(a.w) << 16);
    v.z = (unsigned)f2bf(b.x) | ((unsigned)f2bf(b.y) << 16);
    v.w = (unsigned)f2bf(b.z) | ((unsigned)f2bf(b.w) << 16);
    return v;
}

__device__ __forceinline__ float4 neg4(float4 v) {
    return make_float4(-v.x, -v.y, -v.z, -v.w);
}

__device__ __forceinline__ void async16(const void* g, void* l) {
    __builtin_amdgcn_global_load_lds(
        (const __attribute__((address_space(1))) unsigned int*)g,
        (__attribute__((address_space(3))) unsigned int*)l,
        16, 0, 0);
}

__device__ __forceinline__ float sigm(float x) { return 1.0f / (1.0f + __expf(-x)); }
__device__ __forceinline__ float tanh_(float x) {
    float e = __expf(2.0f * x);          // |x| <~ 10 here, no overflow
    return (e - 1.0f) / (e + 1.0f);
}

// ------------------ merged pack: X rows + W (signs folded) + bias -----------
__global__ __launch_bounds__(256) void pack_all(
    const float* __restrict__ input, const float* __restrict__ hx,
    const float* __restrict__ Uw_r, const float* __restrict__ Uw_i,
    const float* __restrict__ Ww_r, const float* __restrict__ Ww_i,
    const float* __restrict__ Ub_r, const float* __restrict__ Ub_i,
    const float* __restrict__ Wb_r, const float* __restrict__ Wb_i,
    unsigned short* __restrict__ Xb, unsigned short* __restrict__ Wb16,
    float* __restrict__ biasp) {
    int bid = blockIdx.x;
    if (bid < 8192) {
        // ---- pack X = [input | h_x] rows ----
        int idx = bid * 256 + threadIdx.x;          // 2,097,152 chunks of 8
        int r    = idx >> 9;                        // row 0..4095
        int gcol = (idx & 511) * 8;                 // 0..4088
        const float* src = (gcol < 2048) ? (input + (size_t)r * 2048 + gcol)
                                         : (hx    + (size_t)r * 2048 + (gcol - 2048));
        float4 f0 = *(const float4*)src;
        float4 f1 = *(const float4*)(src + 4);
        *(u32x4*)(Xb + (size_t)idx * 8) = pack8(f0, f1);
    } else {
        // ---- pack W row-pairs + bias ----
        int idx = (bid - 8192) * 256 + threadIdx.x; // 2,097,152
        int np = idx >> 9;                          // o*4 + g, 0..4095
        int c8 = idx & 511;
        int k  = c8 * 8;                            // 0..4088
        int o = np >> 2, g = np & 3;
        int q = k >> 10, d = k & 1023;              // k-quarter, offset within
        size_t sidx = (size_t)g * (1024 * 1024) + (size_t)o * 1024 + d;
        const float* srcR = (q < 2 ? Uw_r : Ww_r) + sidx;
        const float* srcI = (q < 2 ? Uw_i : Ww_i) + sidx;
        float4 r0 = *(const float4*)srcR; float4 r1 = *(const float4*)(srcR + 4);
        float4 i0 = *(const float4*)srcI; float4 i1 = *(const float4*)(srcI + 4);
        int n0 = o * 8 + g * 2;
        u32x4 p0, p1;
        if (q & 1) { p0 = pack8(neg4(i0), neg4(i1)); p1 = pack8(r0, r1); }
        else       { p0 = pack8(r0, r1);             p1 = pack8(i0, i1); }
        *(u32x4*)(Wb16 + (size_t)n0 * KDIM + k)       = p0;
        *(u32x4*)(Wb16 + (size_t)(n0 + 1) * KDIM + k) = p1;
        if (c8 == 0) {
            size_t bi = (size_t)g * 1024 + o;
            biasp[n0]     = Ub_r[bi] + Wb_r[bi];
            biasp[n0 + 1] = Ub_i[bi] + Wb_i[bi];
        }
    }
}

// ------------------------- GEMM + fused epilogue ----------------------------
// block: 256 threads (4 waves, 2x2), C-tile 128x128, BK=64, 16x16x32 bf16 MFMA
// LDS exactly 32 KiB; VGPR ~88 -> 5 blocks/CU (5*32768 = 160 KiB, 512/5>=88).
__global__ __launch_bounds__(256) void clstm_gemm(
    const unsigned short* __restrict__ Xb,    // 4096 x 4096 bf16
    const unsigned short* __restrict__ Wb,    // 8192 x 4096 bf16
    const float* __restrict__ biasp,          // 8192
    const float* __restrict__ c_x,            // 4096 x 2048 fp32
    float* __restrict__ out) {
    __shared__ __align__(16) char smem[32768];  // staging 32KB; epilogue 4x8KB
    char* sA = smem;              // 128 x 64 bf16, row stride 128B, chunk-swizzled
    char* sB = smem + 16384;

    const int tid  = threadIdx.x;
    const int lane = tid & 63;
    const int wave = tid >> 6;
    const int wm = wave >> 1, wn = wave & 1;
    const int quad = lane >> 4, col16 = lane & 15;

    // 4x8 supertile swizzle: 32 consecutive blocks share 4 A-stripes +
    // 8 B-stripes (12 MB) instead of 1 A-stripe + 32 B-stripes (33 MB).
    const int bid = blockIdx.x;
    const int st = bid >> 5;                  // 0..63 supertile
    const int wi = bid & 31;                  // 0..31 within
    const int mblock = (st & 7) * 4 + (wi & 3);    // 0..31
    const int nblock = (st >> 3) * 8 + (wi >> 2);  // 0..63

    // staging: lane writes LDS at waveBase + lane*16; global addr carries the
    // XOR swizzle: LDS slot s of row r holds global chunk s ^ (r&7)
    const int rbase = tid >> 3;                       // 0..31
    const int csw   = (tid & 7) ^ (rbase & 7);        // swizzled chunk 0..7
    const unsigned short* pa[4];
    const unsigned short* pb[4];
#pragma unroll
    for (int i = 0; i < 4; ++i) {
        pa[i] = Xb + (size_t)(mblock * 128 + i * 32 + rbase) * KDIM + csw * 8;
        pb[i] = Wb + (size_t)(nblock * 128 + i * 32 + rbase) * KDIM + csw * 8;
    }

    f32x4 acc[4][4] = {};

    for (int kt = 0; kt < 64; ++kt) {
        __syncthreads();                       // prev tile's reads done
#pragma unroll
        for (int i = 0; i < 4; ++i) {
            async16(pa[i], sA + i * 4096 + wave * 1024);
            async16(pb[i], sB + i * 4096 + wave * 1024);
            pa[i] += 64; pb[i] += 64;
        }
        __syncthreads();                       // vmcnt(0) drain + barrier
#pragma unroll
        for (int s = 0; s < 2; ++s) {
            bf16x8 af[4], bf[4];
#pragma unroll
            for (int t = 0; t < 4; ++t) {
                int mr = wm * 64 + t * 16 + col16;
                int ch = (s * 4 + quad) ^ (mr & 7);
                af[t] = *(const bf16x8*)(sA + mr * 128 + ch * 16);
                int nr = wn * 64 + t * 16 + col16;
                int ch2 = (s * 4 + quad) ^ (nr & 7);
                bf[t] = *(const bf16x8*)(sB + nr * 128 + ch2 * 16);
            }
#pragma unroll
            for (int tm = 0; tm < 4; ++tm)
#pragma unroll
                for (int tn = 0; tn < 4; ++tn)
                    acc[tm][tn] = __builtin_amdgcn_mfma_f32_16x16x32_bf16(
                        af[tm], bf[tn], acc[tm][tn], 0, 0, 0);
        }
    }

    // ---- epilogue: per-wave LDS round trip, C-layout -> (row, o) layout ----
    // zs is WAVE-PRIVATE (disjoint 8KB regions): one barrier total, then only
    // intra-wave lgkmcnt ordering (compiler-inserted) is needed.
    __syncthreads();                             // all waves' K-loop LDS reads done
    float* zs = (float*)(smem + wave * 8192);    // 32 rows x 40 f32 = 5120B used
    const float* bp = biasp + nblock * 128 + wn * 64;
    const int o_idx = lane & 3;
    const int rgrp  = lane >> 2;                 // 0..15

    for (int p = 0; p < 4; ++p) {                // {col half h} x {row seg}
        const int h   = p >> 1;
        const int seg = p & 1;                   // tm base = seg*2
#pragma unroll
        for (int tm2 = 0; tm2 < 2; ++tm2)
#pragma unroll
            for (int tl = 0; tl < 2; ++tl) {
                int tn = h * 2 + tl;
                int colz = tl * 16 + col16;
#pragma unroll
                for (int r = 0; r < 4; ++r)
                    zs[(tm2 * 16 + quad * 4 + r) * 40 + colz] = acc[seg * 2 + tm2][tn][r];
            }
        // intra-wave RAW through LDS: compiler inserts lgkmcnt wait

        float4 bb0 = *(const float4*)(bp + h * 32 + o_idx * 8);
        float4 bb1 = *(const float4*)(bp + h * 32 + o_idx * 8 + 4);
        int o_glob = nblock * 16 + wn * 8 + h * 4 + o_idx;

#pragma unroll
        for (int t = 0; t < 2; ++t) {
            int rowz = rgrp + t * 16;            // 0..31 within segment
            const float* zp = zs + rowz * 40 + o_idx * 8;
            float4 z0 = *(const float4*)zp;
            float4 z1 = *(const float4*)(zp + 4);
            int b = mblock * 128 + wm * 64 + seg * 32 + rowz;

            float fr = sigm(z0.x + bb0.x), fi = sigm(z0.y + bb0.y);
            float ir = sigm(z0.z + bb0.z), ii = sigm(z0.w + bb0.w);
            float ar = tanh_(z1.x + bb1.x), ai = tanh_(z1.y + bb1.y);
            float og_r = sigm(z1.z + bb1.z), og_i = sigm(z1.w + bb1.w);

            float cr = c_x[(size_t)b * 2048 + o_glob];
            float ci = c_x[(size_t)b * 2048 + 1024 + o_glob];

            float ct_r = (cr * fr - ci * fi) + (ar * ir - ai * ii);
            float ct_i = (cr * fi + ci * fr) + (ar * ii + ai * ir);
            float tr = tanh_(ct_r), ti = tanh_(ct_i);
            float ht_r = og_r * tr - og_i * ti;
            float ht_i = og_r * ti + og_i * tr;

            out[(size_t)b * 2048 + o_glob]               = ht_r;
            out[(size_t)b * 2048 + 1024 + o_glob]        = ht_i;
            out[HOFF + (size_t)b * 2048 + o_glob]        = ct_r;
            out[HOFF + (size_t)b * 2048 + 1024 + o_glob] = ct_i;
        }
        if (p < 3) __builtin_amdgcn_s_waitcnt(0);  // drain LDS reads before next
                                                   // pass overwrites zs (wave-
                                                   // private; no barrier needed)
    }
}

// ---------------------------------------------------------------------------
extern "C" void kernel_launch(void* const* d_in, const int* in_sizes, int n_in,
                              void* d_out, int out_size, void* d_ws, size_t ws_size,
                              hipStream_t stream) {
    const float* input = (const float*)d_in[0];
    const float* h_x   = (const float*)d_in[1];
    const float* c_x   = (const float*)d_in[2];
    const float* Uw_r  = (const float*)d_in[3];
    const float* Uw_i  = (const float*)d_in[4];
    const float* Ub_r  = (const float*)d_in[5];
    const float* Ub_i  = (const float*)d_in[6];
    const float* Ww_r  = (const float*)d_in[7];
    const float* Ww_i  = (const float*)d_in[8];
    const float* Wb_r  = (const float*)d_in[9];
    const float* Wb_i  = (const float*)d_in[10];
    float* out = (float*)d_out;

    // ws layout: X bf16 (32MB) | Wbig bf16 (64MB) | bias fp32 (32KB)  ~= 96MB
    unsigned short* Xb   = (unsigned short*)d_ws;
    unsigned short* Wb16 = Xb + (size_t)4096 * 4096;
    float* biasp = (float*)(Wb16 + (size_t)8192 * 4096);

    pack_all<<<16384, 256, 0, stream>>>(input, h_x, Uw_r, Uw_i, Ww_r, Ww_i,
                                        Ub_r, Ub_i, Wb_r, Wb_i, Xb, Wb16, biasp);
    clstm_gemm<<<2048, 256, 0, stream>>>(Xb, Wb16, biasp, c_x, out);
}